// Round 1
// baseline (465.810 us; speedup 1.0000x reference)
//
#include <hip/hip_runtime.h>

// Grouped GRU: G=64 groups, D=16 in-dim, H=8 hidden, B=64, T=512.
// One cell = one (b,g) pair = independent GRU. 8 lanes per cell (lane = hidden idx).
// Fully fused: input projection computed on the fly (no gx materialization).

#define Gn 64
#define Dn 16
#define Hn 8
#define Bn 64
#define Tn 512

__device__ __forceinline__ float sigmoid_fast(float x) {
    return 1.0f / (1.0f + __expf(-x));
}
__device__ __forceinline__ float tanh_fast(float x) {
    // 1 - 2/(exp(2x)+1); saturates correctly at +/-inf
    return 1.0f - 2.0f / (__expf(2.0f * x) + 1.0f);
}

__global__ __launch_bounds__(256) void mcgru_kernel(
    const float* __restrict__ x,     // [B, T, G*D]
    const float* __restrict__ W_ih,  // [G, 3H, D]
    const float* __restrict__ W_hh,  // [G, 3H, H]
    const float* __restrict__ b_ih,  // [G, 3H]
    const float* __restrict__ b_hh,  // [G, 3H]
    float* __restrict__ out)         // [B, T, G, H]
{
    const int tid  = blockIdx.x * blockDim.x + threadIdx.x;
    const int cell = tid >> 3;        // 4096 cells
    const int l    = tid & 7;         // hidden index owned by this lane
    const int g    = cell & (Gn - 1);
    const int b    = cell >> 6;

    // ---- preload weights into registers (held across the whole T loop) ----
    float wih[3][Dn];   // gate rows r,z,n of W_ih[g, q*H+l, :]
    float whh[3][Hn];
    float bi[3], bh[3];
#pragma unroll
    for (int q = 0; q < 3; ++q) {
        const int k = q * Hn + l;
        const float4* wr = (const float4*)(W_ih + ((size_t)g * 24 + k) * Dn);
#pragma unroll
        for (int i = 0; i < 4; ++i) {
            float4 v = wr[i];
            wih[q][4*i+0] = v.x; wih[q][4*i+1] = v.y;
            wih[q][4*i+2] = v.z; wih[q][4*i+3] = v.w;
        }
        const float4* hr = (const float4*)(W_hh + ((size_t)g * 24 + k) * Hn);
#pragma unroll
        for (int i = 0; i < 2; ++i) {
            float4 v = hr[i];
            whh[q][4*i+0] = v.x; whh[q][4*i+1] = v.y;
            whh[q][4*i+2] = v.z; whh[q][4*i+3] = v.w;
        }
        bi[q] = b_ih[g * 24 + k];
        bh[q] = b_hh[g * 24 + k];
    }

    const float* xp = x   + ((size_t)b * Tn * Gn + g) * Dn;      // += G*D per t
    float*       op = out + ((size_t)b * Tn * Gn + g) * Hn + l;  // += G*H per t

    // ---- prologue: load x[t=0], compute its gate projection ----
    float gx[3];
    {
        float xv[Dn];
        const float4* p = (const float4*)xp;
#pragma unroll
        for (int i = 0; i < 4; ++i) {
            float4 v = p[i];
            xv[4*i+0] = v.x; xv[4*i+1] = v.y; xv[4*i+2] = v.z; xv[4*i+3] = v.w;
        }
#pragma unroll
        for (int q = 0; q < 3; ++q) {
            float a = bi[q];
#pragma unroll
            for (int d = 0; d < Dn; ++d) a = fmaf(wih[q][d], xv[d], a);
            gx[q] = a;
        }
    }

    float h = 0.0f;
    for (int t = 0; t < Tn; ++t) {
        // prefetch x[t+1] early (independent of the recurrent chain)
        float xn[Dn];
        {
            const int tn = (t + 1 < Tn) ? t + 1 : t;
            const float4* p = (const float4*)(xp + (size_t)tn * Gn * Dn);
#pragma unroll
            for (int i = 0; i < 4; ++i) {
                float4 v = p[i];
                xn[4*i+0] = v.x; xn[4*i+1] = v.y; xn[4*i+2] = v.z; xn[4*i+3] = v.w;
            }
        }

        // gather full h vector across the 8-lane group (one level of bpermute)
        float hj[Hn];
#pragma unroll
        for (int j = 0; j < Hn; ++j) hj[j] = __shfl(h, j, 8);

        float gh[3];
#pragma unroll
        for (int q = 0; q < 3; ++q) {
            float a = bh[q];
#pragma unroll
            for (int j = 0; j < Hn; ++j) a = fmaf(whh[q][j], hj[j], a);
            gh[q] = a;
        }

        const float r = sigmoid_fast(gx[0] + gh[0]);
        const float z = sigmoid_fast(gx[1] + gh[1]);
        const float n = tanh_fast(fmaf(r, gh[2], gx[2]));
        h = fmaf(z, h - n, n);   // (1-z)*n + z*h

        op[(size_t)t * Gn * Hn] = h;

        // input projection for step t+1 — fills latency bubbles of the chain above
#pragma unroll
        for (int q = 0; q < 3; ++q) {
            float a = bi[q];
#pragma unroll
            for (int d = 0; d < Dn; ++d) a = fmaf(wih[q][d], xn[d], a);
            gx[q] = a;
        }
    }
}

extern "C" void kernel_launch(void* const* d_in, const int* in_sizes, int n_in,
                              void* d_out, int out_size, void* d_ws, size_t ws_size,
                              hipStream_t stream) {
    const float* x    = (const float*)d_in[0];
    const float* W_ih = (const float*)d_in[1];
    const float* W_hh = (const float*)d_in[2];
    const float* b_ih = (const float*)d_in[3];
    const float* b_hh = (const float*)d_in[4];
    float* out = (float*)d_out;

    // 4096 cells * 8 lanes = 32768 threads
    dim3 grid(128), block(256);
    hipLaunchKernelGGL(mcgru_kernel, grid, block, 0, stream,
                       x, W_ih, W_hh, b_ih, b_hh, out);
}

// Round 2
// 449.038 us; speedup vs baseline: 1.0374x; 1.0374x over previous
//
#include <hip/hip_runtime.h>

// Grouped GRU: G=64 groups, D=16 in-dim, H=8 hidden, B=64, T=512.
// One cell = one (b,g) pair = independent GRU. 8 lanes per cell (lane = hidden idx).
// Fully fused: input projection computed on the fly (no gx materialization).
//
// R2: __launch_bounds__(64, 1) — default backend heuristic capped us at 64 VGPRs
// (targeting 8 waves/SIMD we can never use: only 512 waves exist in the whole
// problem) and re-loaded weights every timestep. 1 wave/EU unlocks ~512 VGPRs so
// wih[48]+whh[24]+biases stay register-resident across all 512 steps.
// Grid 512x64 spreads waves over all 256 CUs (2/CU) instead of 128 CUs (4/CU).

#define Gn 64
#define Dn 16
#define Hn 8
#define Bn 64
#define Tn 512

__device__ __forceinline__ float sigmoid_fast(float x) {
    return 1.0f / (1.0f + __expf(-x));
}
__device__ __forceinline__ float tanh_fast(float x) {
    // 1 - 2/(exp(2x)+1); saturates correctly at +/-inf
    return 1.0f - 2.0f / (__expf(2.0f * x) + 1.0f);
}

__global__ __launch_bounds__(64, 1) void mcgru_kernel(
    const float* __restrict__ x,     // [B, T, G*D]
    const float* __restrict__ W_ih,  // [G, 3H, D]
    const float* __restrict__ W_hh,  // [G, 3H, H]
    const float* __restrict__ b_ih,  // [G, 3H]
    const float* __restrict__ b_hh,  // [G, 3H]
    float* __restrict__ out)         // [B, T, G, H]
{
    const int tid  = blockIdx.x * blockDim.x + threadIdx.x;
    const int cell = tid >> 3;        // 4096 cells
    const int l    = tid & 7;         // hidden index owned by this lane
    const int g    = cell & (Gn - 1);
    const int b    = cell >> 6;

    // ---- preload weights into registers (held across the whole T loop) ----
    float wih[3][Dn];   // gate rows r,z,n of W_ih[g, q*H+l, :]
    float whh[3][Hn];
    float bi[3], bh[3];
#pragma unroll
    for (int q = 0; q < 3; ++q) {
        const int k = q * Hn + l;
        const float4* wr = (const float4*)(W_ih + ((size_t)g * 24 + k) * Dn);
#pragma unroll
        for (int i = 0; i < 4; ++i) {
            float4 v = wr[i];
            wih[q][4*i+0] = v.x; wih[q][4*i+1] = v.y;
            wih[q][4*i+2] = v.z; wih[q][4*i+3] = v.w;
        }
        const float4* hr = (const float4*)(W_hh + ((size_t)g * 24 + k) * Hn);
#pragma unroll
        for (int i = 0; i < 2; ++i) {
            float4 v = hr[i];
            whh[q][4*i+0] = v.x; whh[q][4*i+1] = v.y;
            whh[q][4*i+2] = v.z; whh[q][4*i+3] = v.w;
        }
        bi[q] = b_ih[g * 24 + k];
        bh[q] = b_hh[g * 24 + k];
    }

    const float* xp = x   + ((size_t)b * Tn * Gn + g) * Dn;      // += G*D per t
    float*       op = out + ((size_t)b * Tn * Gn + g) * Hn + l;  // += G*H per t

    // ---- prologue: load x[t=0], compute its gate projection ----
    float gx[3];
    {
        float xv[Dn];
        const float4* p = (const float4*)xp;
#pragma unroll
        for (int i = 0; i < 4; ++i) {
            float4 v = p[i];
            xv[4*i+0] = v.x; xv[4*i+1] = v.y; xv[4*i+2] = v.z; xv[4*i+3] = v.w;
        }
#pragma unroll
        for (int q = 0; q < 3; ++q) {
            float a = bi[q];
#pragma unroll
            for (int d = 0; d < Dn; ++d) a = fmaf(wih[q][d], xv[d], a);
            gx[q] = a;
        }
    }

    float h = 0.0f;
    for (int t = 0; t < Tn; ++t) {
        // prefetch x[t+1] early (independent of the recurrent chain)
        float xn[Dn];
        {
            const int tn = (t + 1 < Tn) ? t + 1 : t;
            const float4* p = (const float4*)(xp + (size_t)tn * Gn * Dn);
#pragma unroll
            for (int i = 0; i < 4; ++i) {
                float4 v = p[i];
                xn[4*i+0] = v.x; xn[4*i+1] = v.y; xn[4*i+2] = v.z; xn[4*i+3] = v.w;
            }
        }

        // gather full h vector across the 8-lane group (ds_bpermute x8, one wait)
        float hj[Hn];
#pragma unroll
        for (int j = 0; j < Hn; ++j) hj[j] = __shfl(h, j, 8);

        float gh[3];
#pragma unroll
        for (int q = 0; q < 3; ++q) {
            float a = bh[q];
#pragma unroll
            for (int j = 0; j < Hn; ++j) a = fmaf(whh[q][j], hj[j], a);
            gh[q] = a;
        }

        const float r = sigmoid_fast(gx[0] + gh[0]);
        const float z = sigmoid_fast(gx[1] + gh[1]);
        const float n = tanh_fast(fmaf(r, gh[2], gx[2]));
        h = fmaf(z, h - n, n);   // (1-z)*n + z*h

        op[(size_t)t * Gn * Hn] = h;

        // input projection for step t+1 — independent work that fills the
        // latency bubbles of the recurrent chain above
#pragma unroll
        for (int q = 0; q < 3; ++q) {
            float a = bi[q];
#pragma unroll
            for (int d = 0; d < Dn; ++d) a = fmaf(wih[q][d], xn[d], a);
            gx[q] = a;
        }
    }
}

extern "C" void kernel_launch(void* const* d_in, const int* in_sizes, int n_in,
                              void* d_out, int out_size, void* d_ws, size_t ws_size,
                              hipStream_t stream) {
    const float* x    = (const float*)d_in[0];
    const float* W_ih = (const float*)d_in[1];
    const float* W_hh = (const float*)d_in[2];
    const float* b_ih = (const float*)d_in[3];
    const float* b_hh = (const float*)d_in[4];
    float* out = (float*)d_out;

    // 4096 cells * 8 lanes = 32768 threads = 512 waves; 1 wave per block
    // spreads them across all 256 CUs (2 waves/CU).
    dim3 grid(512), block(64);
    hipLaunchKernelGGL(mcgru_kernel, grid, block, 0, stream,
                       x, W_ih, W_hh, b_ih, b_hh, out);
}

// Round 3
// 421.003 us; speedup vs baseline: 1.1064x; 1.0666x over previous
//
#include <hip/hip_runtime.h>

// Grouped GRU: G=64 groups, D=16 in-dim, H=8 hidden, B=64, T=512.
// One cell = one (b,g) pair = independent GRU. 8 lanes per cell (lane = hidden idx).
// Fully fused: input projection computed on the fly (no gx materialization).
//
// R3: (a) asm-pin the preloaded weights so the compiler cannot sink/remat the
// loads into the T-loop (R2 showed VGPR_Count stuck at 64 = weights re-fetched
// every step); (b) amdgpu_waves_per_eu(1,1) so the register budget is ~512 and
// the pinned values live in VGPRs, not scratch; (c) x prefetched 4 timesteps
// ahead (two buffers, loop unrolled x2) so the HBM latency (~900 cyc) is
// covered by ~2 recurrent-chain lengths; (d) nontemporal out stores.

#define Gn 64
#define Dn 16
#define Hn 8
#define Bn 64
#define Tn 512

__device__ __forceinline__ float sigmoid_fast(float x) {
    return 1.0f / (1.0f + __expf(-x));
}
__device__ __forceinline__ float tanh_fast(float x) {
    // 1 - 2/(exp(2x)+1); saturates correctly at +/-inf
    return 1.0f - 2.0f / (__expf(2.0f * x) + 1.0f);
}

__global__ __attribute__((amdgpu_flat_work_group_size(64, 64),
                          amdgpu_waves_per_eu(1, 1)))
void mcgru_kernel(
    const float* __restrict__ x,     // [B, T, G*D]
    const float* __restrict__ W_ih,  // [G, 3H, D]
    const float* __restrict__ W_hh,  // [G, 3H, H]
    const float* __restrict__ b_ih,  // [G, 3H]
    const float* __restrict__ b_hh,  // [G, 3H]
    float* __restrict__ out)         // [B, T, G, H]
{
    const int tid  = blockIdx.x * blockDim.x + threadIdx.x;
    const int cell = tid >> 3;        // 4096 cells
    const int l    = tid & 7;         // hidden index owned by this lane
    const int g    = cell & (Gn - 1);
    const int b    = cell >> 6;

    // ---- preload weights into registers (held across the whole T loop) ----
    float wih[3][Dn];   // gate rows r,z,n of W_ih[g, q*H+l, :]
    float whh[3][Hn];
    float bi[3], bh[3];
#pragma unroll
    for (int q = 0; q < 3; ++q) {
        const int k = q * Hn + l;
        const float4* wr = (const float4*)(W_ih + ((size_t)g * 24 + k) * Dn);
#pragma unroll
        for (int i = 0; i < 4; ++i) {
            float4 v = wr[i];
            wih[q][4*i+0] = v.x; wih[q][4*i+1] = v.y;
            wih[q][4*i+2] = v.z; wih[q][4*i+3] = v.w;
        }
        const float4* hr = (const float4*)(W_hh + ((size_t)g * 24 + k) * Hn);
#pragma unroll
        for (int i = 0; i < 2; ++i) {
            float4 v = hr[i];
            whh[q][4*i+0] = v.x; whh[q][4*i+1] = v.y;
            whh[q][4*i+2] = v.z; whh[q][4*i+3] = v.w;
        }
        bi[q] = b_ih[g * 24 + k];
        bh[q] = b_hh[g * 24 + k];
    }

    // Pin every preloaded value: makes them opaque so the compiler cannot
    // rematerialize the global loads inside the loop — they must stay live.
#pragma unroll
    for (int q = 0; q < 3; ++q) {
#pragma unroll
        for (int d = 0; d < Dn; ++d) asm volatile("" : "+v"(wih[q][d]));
#pragma unroll
        for (int j = 0; j < Hn; ++j) asm volatile("" : "+v"(whh[q][j]));
        asm volatile("" : "+v"(bi[q]));
        asm volatile("" : "+v"(bh[q]));
    }

    const float* xp = x   + ((size_t)b * Tn * Gn + g) * Dn;      // += G*D per t
    float*       op = out + ((size_t)b * Tn * Gn + g) * Hn + l;  // += G*H per t

    auto load_x = [&](int t, float* xv) {
        const float4* p = (const float4*)(xp + (size_t)t * Gn * Dn);
#pragma unroll
        for (int i = 0; i < 4; ++i) {
            float4 v = p[i];
            xv[4*i+0] = v.x; xv[4*i+1] = v.y; xv[4*i+2] = v.z; xv[4*i+3] = v.w;
        }
    };
    auto proj = [&](const float* xv, float* gx) {
#pragma unroll
        for (int q = 0; q < 3; ++q) {
            float a = bi[q];
#pragma unroll
            for (int d = 0; d < Dn; ++d) a = fmaf(wih[q][d], xv[d], a);
            gx[q] = a;
        }
    };

    float h = 0.0f;
    auto step = [&](const float* gx, int t) {
        float hj[Hn];
#pragma unroll
        for (int j = 0; j < Hn; ++j) hj[j] = __shfl(h, j, 8);
        float gh[3];
#pragma unroll
        for (int q = 0; q < 3; ++q) {
            float a = bh[q];
#pragma unroll
            for (int j = 0; j < Hn; ++j) a = fmaf(whh[q][j], hj[j], a);
            gh[q] = a;
        }
        const float r = sigmoid_fast(gx[0] + gh[0]);
        const float z = sigmoid_fast(gx[1] + gh[1]);
        const float n = tanh_fast(fmaf(r, gh[2], gx[2]));
        h = fmaf(z, h - n, n);   // (1-z)*n + z*h
        __builtin_nontemporal_store(h, op + (size_t)t * Gn * Hn);
    };

    // ---- software pipeline: gx ready 2 steps ahead, x in flight 4 ahead ----
    float gxa[3], gxb[3];     // gate projections for steps t (a) and t+1 (b)
    float xva[Dn], xvb[Dn];   // raw x for steps t+2 (a) and t+3 (b)
    {
        float xv[Dn];
        load_x(0, xv); proj(xv, gxa);
        load_x(1, xv); proj(xv, gxb);
    }
    load_x(2, xva);
    load_x(3, xvb);

    for (int t = 0; t < Tn; t += 2) {
        step(gxa, t);                    // recurrent chain, uses gx of step t
        proj(xva, gxa);                  // consume x[t+2] -> gx for step t+2
        {
            int tn = t + 4; if (tn > Tn - 1) tn = Tn - 1;
            load_x(tn, xva);             // in flight for ~2 step-chains
        }
        step(gxb, t + 1);
        proj(xvb, gxb);                  // consume x[t+3] -> gx for step t+3
        {
            int tn = t + 5; if (tn > Tn - 1) tn = Tn - 1;
            load_x(tn, xvb);
        }
    }
}

extern "C" void kernel_launch(void* const* d_in, const int* in_sizes, int n_in,
                              void* d_out, int out_size, void* d_ws, size_t ws_size,
                              hipStream_t stream) {
    const float* x    = (const float*)d_in[0];
    const float* W_ih = (const float*)d_in[1];
    const float* W_hh = (const float*)d_in[2];
    const float* b_ih = (const float*)d_in[3];
    const float* b_hh = (const float*)d_in[4];
    float* out = (float*)d_out;

    // 4096 cells * 8 lanes = 32768 threads = 512 waves; 1 wave per block
    // spreads them across all 256 CUs (2 waves/CU).
    dim3 grid(512), block(64);
    hipLaunchKernelGGL(mcgru_kernel, grid, block, 0, stream,
                       x, W_ih, W_hh, b_ih, b_hh, out);
}

// Round 5
// 344.202 us; speedup vs baseline: 1.3533x; 1.2231x over previous
//
#include <hip/hip_runtime.h>

// Grouped GRU: G=64 groups, D=16 in-dim, H=8 hidden, B=64, T=512.
// One cell = one (b,g) pair; 8 lanes per cell (lane l = hidden index).
// Fully fused: input projection on the fly, weights register-resident.
//
// R5 = R4 with the tanh sign bug fixed: R4 computed 1-2/(1+exp(-2a)) which is
// -tanh(a). Correct identity: tanh(a) = 1 - 2/(exp(+2a)+1).
//
// R4 design: (a) h all-gather via DPP (quad_perm xor1/2/3 + row_half_mirror)
// — pure VALU, no ds_bpermute / lgkmcnt(0) wait on the recurrent critical
// path; W_hh columns pre-permuted per lane (jmap) to match DPP register
// order. (b) raw v_rcp/v_exp for the gates — avoids the full-precision
// divide sequence (~25 VALU/step). (c) gh as two 4-FMA partial chains;
// h' = fma(n, 1-z, z*h) so only one op follows n. (d) x prefetch distance 8
// steps (4 buffers, unroll x4).

#define Gn 64
#define Dn 16
#define Hn 8
#define Tn 512

__device__ __forceinline__ float rcp_fast(float v) { return __builtin_amdgcn_rcpf(v); }
__device__ __forceinline__ float exp2_fast(float v) { return __builtin_amdgcn_exp2f(v); }

#define K_NEG_LOG2E  (-1.44269504088896340736f)
#define K_POS2_LOG2E ( 2.88539008177792681472f)

template <int CTRL>
__device__ __forceinline__ float dppf(float v) {
    return __int_as_float(
        __builtin_amdgcn_update_dpp(0, __float_as_int(v), CTRL, 0xF, 0xF, false));
}

__global__ __attribute__((amdgpu_flat_work_group_size(64, 64),
                          amdgpu_waves_per_eu(1, 1)))
void mcgru_kernel(
    const float* __restrict__ x,     // [B, T, G*D]
    const float* __restrict__ W_ih,  // [G, 3H, D]
    const float* __restrict__ W_hh,  // [G, 3H, H]
    const float* __restrict__ b_ih,  // [G, 3H]
    const float* __restrict__ b_hh,  // [G, 3H]
    float* __restrict__ out)         // [B, T, G, H]
{
    const int tid  = blockIdx.x * blockDim.x + threadIdx.x;
    const int cell = tid >> 3;        // 4096 cells
    const int l    = tid & 7;         // hidden index owned by this lane
    const int g    = cell & (Gn - 1);
    const int b    = cell >> 6;
    const int s    = l & 3;           // position within quad
    const int q    = l >> 2;          // quad within octet

    // DPP gather register order: H[k] holds h[jmap[k]] (octet-local index).
    // jmap[k] = l XOR m_k, m = {0,1,2,3,7,6,5,4} — a bijection on 0..7.
    int jmap[8];
#pragma unroll
    for (int k = 0; k < 8; ++k) {
        const int hi2 = k >> 2, r = k & 3;
        jmap[k] = ((q ^ hi2) << 2) | (s ^ r ^ (hi2 ? 3 : 0));
    }

    // ---- preload weights (register-resident across the whole T loop) ----
    float wih[3][Dn];   // W_ih[g, qg*H+l, :]
    float whh[3][8];    // W_hh[g, qg*H+l, jmap[k]]  (column-permuted for DPP order)
    float bi[3], bh[3];
#pragma unroll
    for (int qg = 0; qg < 3; ++qg) {
        const int row = qg * Hn + l;
        const float4* wr = (const float4*)(W_ih + ((size_t)g * 24 + row) * Dn);
#pragma unroll
        for (int i = 0; i < 4; ++i) {
            float4 v = wr[i];
            wih[qg][4*i+0] = v.x; wih[qg][4*i+1] = v.y;
            wih[qg][4*i+2] = v.z; wih[qg][4*i+3] = v.w;
        }
        const float* hrow = W_hh + ((size_t)g * 24 + row) * Hn;
#pragma unroll
        for (int k = 0; k < 8; ++k) whh[qg][k] = hrow[jmap[k]];
        bi[qg] = b_ih[g * 24 + row];
        bh[qg] = b_hh[g * 24 + row];
    }
    // Pin: compiler cannot sink/remat these loads into the T-loop.
#pragma unroll
    for (int qg = 0; qg < 3; ++qg) {
#pragma unroll
        for (int d = 0; d < Dn; ++d) asm volatile("" : "+v"(wih[qg][d]));
#pragma unroll
        for (int k = 0; k < 8; ++k) asm volatile("" : "+v"(whh[qg][k]));
        asm volatile("" : "+v"(bi[qg]));
        asm volatile("" : "+v"(bh[qg]));
    }

    const float* xp = x   + ((size_t)b * Tn * Gn + g) * Dn;
    float*       op = out + ((size_t)b * Tn * Gn + g) * Hn + l;

    auto load_x = [&](int t, float* xv) {
        const float4* p = (const float4*)(xp + (size_t)t * Gn * Dn);
#pragma unroll
        for (int i = 0; i < 4; ++i) {
            float4 v = p[i];
            xv[4*i+0] = v.x; xv[4*i+1] = v.y; xv[4*i+2] = v.z; xv[4*i+3] = v.w;
        }
    };
    auto proj = [&](const float* xv, float* gx) {
#pragma unroll
        for (int qg = 0; qg < 3; ++qg) {
            float a = bi[qg];
#pragma unroll
            for (int d = 0; d < Dn; ++d) a = fmaf(wih[qg][d], xv[d], a);
            gx[qg] = a;
        }
    };

    float h = 0.0f;
    auto step = [&](const float* gx, int t) {
        // 8-lane all-gather of h, pure VALU (no LDS / lgkmcnt):
        float H[8];
        H[0] = h;
        H[1] = dppf<0xB1>(h);     // quad_perm [1,0,3,2]  = xor 1
        H[2] = dppf<0x4E>(h);     // quad_perm [2,3,0,1]  = xor 2
        H[3] = dppf<0x1B>(h);     // quad_perm [3,2,1,0]  = xor 3
        H[4] = dppf<0x141>(H[0]); // row_half_mirror = xor 7 within the octet
        H[5] = dppf<0x141>(H[1]); // -> xor 6
        H[6] = dppf<0x141>(H[2]); // -> xor 5
        H[7] = dppf<0x141>(H[3]); // -> xor 4

        float gh[3];
#pragma unroll
        for (int qg = 0; qg < 3; ++qg) {
            float a = fmaf(whh[qg][1], H[1], whh[qg][0] * H[0]);
            a = fmaf(whh[qg][2], H[2], a);
            a = fmaf(whh[qg][3], H[3], a);
            float c = fmaf(whh[qg][5], H[5], whh[qg][4] * H[4]);
            c = fmaf(whh[qg][6], H[6], c);
            c = fmaf(whh[qg][7], H[7], c);
            gh[qg] = (bh[qg] + a) + c;
        }

        const float r  = rcp_fast(1.0f + exp2_fast((gx[0] + gh[0]) * K_NEG_LOG2E));
        const float z  = rcp_fast(1.0f + exp2_fast((gx[1] + gh[1]) * K_NEG_LOG2E));
        const float zh = z * h;          // ready before n resolves
        const float om = 1.0f - z;
        const float a  = fmaf(r, gh[2], gx[2]);
        // tanh(a) = 1 - 2/(exp(+2a)+1); exp2(+inf)->inf, rcp(inf)->0 -> n=1;
        // exp2(-inf)->0, rcp(1)->1 -> n=-1. Correct saturation both ways.
        const float e  = exp2_fast(a * K_POS2_LOG2E);
        const float n  = fmaf(-2.0f, rcp_fast(e + 1.0f), 1.0f);
        h = fmaf(n, om, zh);             // (1-z)*n + z*h
        __builtin_nontemporal_store(h, op + (size_t)t * (Gn * Hn));
    };

    // ---- software pipeline: gx ready >=1 step ahead, x in flight 8 steps ----
    float gx[4][3];
    float xv[4][Dn];
#pragma unroll
    for (int i = 0; i < 4; ++i) load_x(i, xv[i]);
#pragma unroll
    for (int i = 0; i < 4; ++i) { proj(xv[i], gx[i]); load_x(4 + i, xv[i]); }

    for (int t = 0; t < Tn; t += 4) {
#pragma unroll
        for (int i = 0; i < 4; ++i) {
            step(gx[i], t + i);          // recurrent chain for step t+i
            proj(xv[i], gx[i]);          // gx for step t+4+i (off critical path)
            int tn = t + 8 + i;
            if (tn > Tn - 1) tn = Tn - 1;
            load_x(tn, xv[i]);           // in flight for ~8 step-chains
        }
    }
}

extern "C" void kernel_launch(void* const* d_in, const int* in_sizes, int n_in,
                              void* d_out, int out_size, void* d_ws, size_t ws_size,
                              hipStream_t stream) {
    const float* x    = (const float*)d_in[0];
    const float* W_ih = (const float*)d_in[1];
    const float* W_hh = (const float*)d_in[2];
    const float* b_ih = (const float*)d_in[3];
    const float* b_hh = (const float*)d_in[4];
    float* out = (float*)d_out;

    // 4096 cells * 8 lanes = 32768 threads = 512 waves; 1 wave/block over 256 CUs.
    dim3 grid(512), block(64);
    hipLaunchKernelGGL(mcgru_kernel, grid, block, 0, stream,
                       x, W_ih, W_hh, b_ih, b_hh, out);
}

// Round 7
// 271.366 us; speedup vs baseline: 1.7165x; 1.2684x over previous
//
#include <hip/hip_runtime.h>

// Grouped GRU: G=64, D=16, H=8, B=64, T=512. One cell per 8 lanes.
// R7 = R6 with the n-gate bias fold fixed. Reference:
//   n = tanh(xn + b_ih_n + r * (hn + b_hh_n))   — b_hh_n is INSIDE r*(...).
// R6 folded b_hh_n additively -> error (1-r)*b_hh_n (absmax 0.32). Now b_hh_n
// stays in its own register (scaled by 2log2e) and seeds gh[2]'s second
// partial chain, so r multiplies it. r,z gates keep the full additive fold.
//
// R6 design (unchanged): (a) PINNED 8-step x-prefetch ring — R5's VGPR=132
// proved the compiler rematerialized x loads at their use, exposing ~900 cyc
// HBM latency per step. Ring slots are asm-pinned 6 bodies after their load.
// (b) packed-fp32 proj (v_pk_fma_f32). (c) gate scales pre-folded into
// weights (-log2e for r,z; +2log2e for n).

#define Gn 64
#define Dn 16
#define Hn 8
#define Tn 512

typedef float v2f __attribute__((ext_vector_type(2)));

__device__ __forceinline__ float rcp_fast(float v) { return __builtin_amdgcn_rcpf(v); }
__device__ __forceinline__ float exp2_fast(float v) { return __builtin_amdgcn_exp2f(v); }

#define KNL (-1.44269504088896340736f)   // -log2(e)
#define KP2 ( 2.88539008177792681472f)   // +2*log2(e)

template <int CTRL>
__device__ __forceinline__ float dppf(float v) {
    return __int_as_float(
        __builtin_amdgcn_update_dpp(0, __float_as_int(v), CTRL, 0xF, 0xF, false));
}

__global__ __attribute__((amdgpu_flat_work_group_size(64, 64),
                          amdgpu_waves_per_eu(1, 1)))
void mcgru_kernel(
    const float* __restrict__ x,     // [B, T, G*D]
    const float* __restrict__ W_ih,  // [G, 3H, D]
    const float* __restrict__ W_hh,  // [G, 3H, H]
    const float* __restrict__ b_ih,  // [G, 3H]
    const float* __restrict__ b_hh,  // [G, 3H]
    float* __restrict__ out)         // [B, T, G, H]
{
    const int tid  = blockIdx.x * blockDim.x + threadIdx.x;
    const int cell = tid >> 3;
    const int l    = tid & 7;
    const int g    = cell & (Gn - 1);
    const int b    = cell >> 6;
    const int s4   = l & 3;
    const int q    = l >> 2;

    // DPP gather order: H[k] = h[jmap[k]], jmap[k] = l ^ {0,1,2,3,7,6,5,4}[k]
    int jmap[8];
#pragma unroll
    for (int k = 0; k < 8; ++k) {
        const int hi2 = k >> 2, r = k & 3;
        jmap[k] = ((q ^ hi2) << 2) | (s4 ^ r ^ (hi2 ? 3 : 0));
    }

    const float scale[3] = {KNL, KNL, KP2};

    // ---- preload weights, pre-scaled ----
    v2f   wih[3][8];    // W_ih row pairs, scaled
    float whh[3][8];    // W_hh columns permuted to DPP order, scaled
    float bs[3];        // r,z: (b_ih+b_hh)*KNL ; n: b_ih*KP2 only
    float bhn;          // n-gate: b_hh * KP2, kept under the r-multiplication
#pragma unroll
    for (int qg = 0; qg < 3; ++qg) {
        const int row = qg * Hn + l;
        const float sc = scale[qg];
        const float4* wr = (const float4*)(W_ih + ((size_t)g * 24 + row) * Dn);
#pragma unroll
        for (int i = 0; i < 4; ++i) {
            float4 v = wr[i];
            wih[qg][2*i+0] = (v2f){v.x * sc, v.y * sc};
            wih[qg][2*i+1] = (v2f){v.z * sc, v.w * sc};
        }
        const float* hrow = W_hh + ((size_t)g * 24 + row) * Hn;
#pragma unroll
        for (int k = 0; k < 8; ++k) whh[qg][k] = hrow[jmap[k]] * sc;
        if (qg < 2) {
            bs[qg] = (b_ih[g * 24 + row] + b_hh[g * 24 + row]) * sc;  // additive fold OK
        } else {
            bs[qg] = b_ih[g * 24 + row] * sc;   // input-side bias only
            bhn    = b_hh[g * 24 + row] * sc;   // stays inside r*(...)
        }
    }
    // Pin weights: no sink/remat into the T loop.
#pragma unroll
    for (int qg = 0; qg < 3; ++qg) {
#pragma unroll
        for (int i = 0; i < 8; ++i) asm volatile("" : "+v"(wih[qg][i]));
#pragma unroll
        for (int k = 0; k < 8; ++k) asm volatile("" : "+v"(whh[qg][k]));
        asm volatile("" : "+v"(bs[qg]));
    }
    asm volatile("" : "+v"(bhn));

    const float* xp = x   + ((size_t)b * Tn * Gn + g) * Dn;
    float*       op = out + ((size_t)b * Tn * Gn + g) * Hn + l;

    auto load_x = [&](int t, v2f* xv) {
        const float4* p = (const float4*)(xp + (size_t)t * Gn * Dn);
#pragma unroll
        for (int i = 0; i < 4; ++i) {
            float4 v = p[i];
            xv[2*i+0] = (v2f){v.x, v.y};
            xv[2*i+1] = (v2f){v.z, v.w};
        }
    };
    auto proj = [&](const v2f* xv, float* gx) {
#pragma unroll
        for (int qg = 0; qg < 3; ++qg) {
            v2f acc = wih[qg][0] * xv[0];
#pragma unroll
            for (int i = 1; i < 8; ++i) acc += wih[qg][i] * xv[i];  // v_pk_fma_f32
            gx[qg] = (bs[qg] + acc.x) + acc.y;
        }
    };

    float h = 0.0f;
    auto step = [&](const float* gx, int t) {
        float H[8];
        H[0] = h;
        H[1] = dppf<0xB1>(h);     // quad_perm xor1
        H[2] = dppf<0x4E>(h);     // quad_perm xor2
        H[3] = dppf<0x1B>(h);     // quad_perm xor3
        H[4] = dppf<0x141>(H[0]); // row_half_mirror = xor7 within octet
        H[5] = dppf<0x141>(H[1]);
        H[6] = dppf<0x141>(H[2]);
        H[7] = dppf<0x141>(H[3]);

        float gh[3];
#pragma unroll
        for (int qg = 0; qg < 3; ++qg) {
            float a = fmaf(whh[qg][1], H[1], whh[qg][0] * H[0]);
            a = fmaf(whh[qg][2], H[2], a);
            a = fmaf(whh[qg][3], H[3], a);
            // n-gate: seed with bhn so r multiplies (hn + b_hh_n), per reference
            float c = (qg == 2) ? fmaf(whh[qg][4], H[4], bhn)
                                : whh[qg][4] * H[4];
            c = fmaf(whh[qg][5], H[5], c);
            c = fmaf(whh[qg][6], H[6], c);
            c = fmaf(whh[qg][7], H[7], c);
            gh[qg] = a + c;
        }
        // weights pre-scaled: r,z rows by -log2e; n rows by +2log2e
        const float r  = rcp_fast(1.0f + exp2_fast(gx[0] + gh[0]));
        const float z  = rcp_fast(1.0f + exp2_fast(gx[1] + gh[1]));
        const float zh = z * h;
        const float om = 1.0f - z;
        const float e  = exp2_fast(fmaf(r, gh[2], gx[2]));
        const float n  = fmaf(-2.0f, rcp_fast(e + 1.0f), 1.0f);  // tanh
        h = fmaf(n, om, zh);
        __builtin_nontemporal_store(h, op + (size_t)t * (Gn * Hn));
    };

    // ---- pipeline: ring of 8 steps of x; proj 2 steps ahead of step ----
    v2f   xv[8][8];     // slot j holds x for a step 8 ahead of its write body
    float gx[2][3];     // gate proj for steps s (slot s&1) and s+1

    {
        v2f t0[8], t1[8];
        load_x(0, t0);
        load_x(1, t1);
        load_x(2, xv[2]); load_x(3, xv[3]); load_x(4, xv[4]);
        load_x(5, xv[5]); load_x(6, xv[6]); load_x(7, xv[7]);
        proj(t0, gx[0]);  // gx for step 0
        proj(t1, gx[1]);  // gx for step 1
    }

    for (int t = 0; t < Tn; t += 8) {
#pragma unroll
        for (int j = 0; j < 8; ++j) {
            const int s = t + j;
            int tl = s + 8; if (tl > Tn - 1) tl = Tn - 1;
            load_x(tl, xv[j]);            // issue early: in flight 6 bodies
            step(gx[j & 1], s);           // recurrent chain for step s
            // pin slot (j+2)&7: its load was issued 6 bodies (~900+ cyc) ago,
            // so the forced vmcnt wait here is free; blocks remat.
#pragma unroll
            for (int i = 0; i < 8; ++i) asm volatile("" : "+v"(xv[(j+2)&7][i]));
            proj(xv[(j+2)&7], gx[j & 1]); // gx for step s+2
        }
    }
}

extern "C" void kernel_launch(void* const* d_in, const int* in_sizes, int n_in,
                              void* d_out, int out_size, void* d_ws, size_t ws_size,
                              hipStream_t stream) {
    const float* x    = (const float*)d_in[0];
    const float* W_ih = (const float*)d_in[1];
    const float* W_hh = (const float*)d_in[2];
    const float* b_ih = (const float*)d_in[3];
    const float* b_hh = (const float*)d_in[4];
    float* out = (float*)d_out;

    // 4096 cells * 8 lanes = 512 waves; 1 wave/block over 256 CUs.
    dim3 grid(512), block(64);
    hipLaunchKernelGGL(mcgru_kernel, grid, block, 0, stream,
                       x, W_ih, W_hh, b_ih, b_hh, out);
}